// Round 1
// baseline (543.024 us; speedup 1.0000x reference)
//
#include <hip/hip_runtime.h>
#include <hip/hip_bf16.h>
#include <stdint.h>

#define L_SEQ 131072
#define H_DIM 256
#define P_DIM 64
#define C2    128     // 2*P (re|im concatenated)
#define T_CH  128     // chunk length
#define NC    1024    // number of chunks

// float-index offsets into workspace
#define WT_OFF   0        // Wt[h][c]   : 256*128
#define W2_OFF   32768    // W2[c][h]   : 128*256
#define LAM_OFF  65536    // lbr[64], lbi[64], gr[64], gi[64]
#define LPRE_OFF 65792    // lambda^(k+1).re : [128][64]
#define LPIM_OFF 73984    // lambda^(k+1).im : [128][64]
#define XIN_OFF  82176    // x_in[NC][128]
#define FR_OFF   213248   // firstReset[NC] (ints)
#define XL_OFF   214272   // x_local bf16 [L][128] starts here (ushort region)

__device__ __forceinline__ uint16_t f2bf(float f){
    uint32_t u = __builtin_bit_cast(uint32_t, f);
    u += 0x7fffu + ((u >> 16) & 1u);
    return (uint16_t)(u >> 16);
}
__device__ __forceinline__ float bf2f(uint16_t h){
    uint32_t u = ((uint32_t)h) << 16;
    return __builtin_bit_cast(float, u);
}

// ---------------- K0a: lambda_bar, g = (lbar-1)/lambda, power table ----------------
__global__ void k0a(const float* __restrict__ Lre, const float* __restrict__ Lim,
                    const float* __restrict__ deltas, float* __restrict__ wsf){
    int p = threadIdx.x;
    if (p >= P_DIM) return;
    float lr = Lre[p], li = Lim[p], dl = deltas[p];
    float er = expf(lr * dl);
    float si, co;
    sincosf(li * dl, &si, &co);
    float lbr = er * co, lbi = er * si;
    float den = lr*lr + li*li;
    float gr = ((lbr - 1.f)*lr + lbi*li) / den;
    float gi = (lbi*lr - (lbr - 1.f)*li) / den;
    wsf[LAM_OFF +       p] = lbr;
    wsf[LAM_OFF +  64 + p] = lbi;
    wsf[LAM_OFF + 128 + p] = gr;
    wsf[LAM_OFF + 192 + p] = gi;
    float pr = lbr, pi = lbi;            // lambda^1
    for (int k = 0; k < T_CH; k++){
        wsf[LPRE_OFF + k*64 + p] = pr;   // lambda^(k+1)
        wsf[LPIM_OFF + k*64 + p] = pi;
        float nr = pr*lbr - pi*lbi;
        float ni = pr*lbi + pi*lbr;
        pr = nr; pi = ni;
    }
}

// ---------------- K0b: weight rearrangement ----------------
// Wt[h][c] : c<64 -> Bbar_re[c][h], c>=64 -> Bbar_im[c-64][h]
// W2[c][h] : c<64 -> 2*C_re[h][c],  c>=64 -> -2*C_im[h][c-64]
__global__ void k0b(const float* __restrict__ Bre, const float* __restrict__ Bim,
                    const float* __restrict__ Cre, const float* __restrict__ Cim,
                    float* __restrict__ wsf){
    int idx = blockIdx.x * 256 + threadIdx.x;
    if (idx < 32768){
        int h = idx >> 7, c = idx & 127;
        int p = c & 63;
        float gr = wsf[LAM_OFF + 128 + p], gi = wsf[LAM_OFF + 192 + p];
        float br = Bre[p*H_DIM + h], bi = Bim[p*H_DIM + h];
        float v = (c < 64) ? (gr*br - gi*bi) : (gr*bi + gi*br);
        wsf[WT_OFF + h*C2 + c] = v;
    } else {
        int i2 = idx - 32768;
        int c = i2 >> 8, h = i2 & 255;
        float v = (c < 64) ? 2.f * Cre[h*P_DIM + c] : -2.f * Cim[h*P_DIM + (c - 64)];
        wsf[W2_OFF + c*H_DIM + h] = v;
    }
}

// ---------------- K1: per-chunk GEMM1 (Bu) + local scan -> x_local(bf16), firstReset ----------------
__global__ __launch_bounds__(256) void k1(const float* __restrict__ u,
                                          const int* __restrict__ dflag,
                                          float* __restrict__ wsf){
    __shared__ float smem[8192];        // [0,4096): u slice [128][32]; [4096,8192): Wt slice [32][128]; later: scan buf [64][128]
    __shared__ int d_lds[T_CH];
    __shared__ int fr_sh;
    const int tid = threadIdx.x;
    const int cc  = blockIdx.x;
    const int t0  = cc * T_CH;
    const int ty  = tid >> 4, tx = tid & 15;
    const int r0  = ty * 8,  c0 = tx * 8;

    if (tid < T_CH) d_lds[tid] = dflag[t0 + tid];
    if (tid == 0) fr_sh = T_CH;
    __syncthreads();
    if (tid < T_CH && d_lds[tid]) atomicMin(&fr_sh, tid);

    float acc[8][8] = {};

    for (int ks = 0; ks < 8; ks++){
        const int k0 = ks * 32;
        __syncthreads();
        #pragma unroll
        for (int i = 0; i < 4; i++){
            int f = tid + i*256;
            int r = f >> 3, q = f & 7;
            float4 v = *(const float4*)(u + (size_t)(t0 + r)*H_DIM + k0 + q*4);
            *(float4*)(smem + r*32 + q*4) = v;
        }
        #pragma unroll
        for (int i = 0; i < 4; i++){
            int f = tid + i*256;
            int kk = f >> 5, q = f & 31;
            float4 v = *(const float4*)(wsf + WT_OFF + (k0 + kk)*C2 + q*4);
            *(float4*)(smem + 4096 + kk*C2 + q*4) = v;
        }
        __syncthreads();
        #pragma unroll 4
        for (int k = 0; k < 32; k++){
            float a[8];
            #pragma unroll
            for (int i = 0; i < 8; i++) a[i] = smem[(r0 + i)*32 + k];
            float4 w0 = *(const float4*)(smem + 4096 + k*C2 + c0);
            float4 w1 = *(const float4*)(smem + 4096 + k*C2 + c0 + 4);
            float w[8] = {w0.x, w0.y, w0.z, w0.w, w1.x, w1.y, w1.z, w1.w};
            #pragma unroll
            for (int i = 0; i < 8; i++)
                #pragma unroll
                for (int j = 0; j < 8; j++)
                    acc[i][j] = fmaf(a[i], w[j], acc[i][j]);
        }
    }

    // sequential local scan (two 64-row halves through LDS), x starts at 0 per chunk
    float lbr = 0.f, lbi = 0.f, xr = 0.f, xi = 0.f;
    if (tid < 64){ lbr = wsf[LAM_OFF + tid]; lbi = wsf[LAM_OFF + 64 + tid]; }
    uint32_t* xl32 = (uint32_t*)(wsf + XL_OFF);

    for (int hh = 0; hh < 2; hh++){
        const int hr0 = hh * 64;
        __syncthreads();                       // previous smem readers done
        if ((ty >> 3) == hh){
            int ty2 = ty & 7;
            #pragma unroll
            for (int i = 0; i < 8; i++){
                int rr = ty2*8 + i;
                #pragma unroll
                for (int j = 0; j < 8; j++) smem[rr*C2 + c0 + j] = acc[i][j];
            }
        }
        __syncthreads();
        if (tid < 64){
            int p = tid;
            for (int t = 0; t < 64; t++){
                int gt = hr0 + t;
                float bur = smem[t*C2 + p];
                float bui = smem[t*C2 + 64 + p];
                if (d_lds[gt]){ xr = bur; xi = bui; }
                else {
                    float nr = fmaf(lbr, xr, fmaf(-lbi, xi, bur));
                    float ni = fmaf(lbr, xi, fmaf( lbi, xr, bui));
                    xr = nr; xi = ni;
                }
                smem[t*C2 + p]      = xr;
                smem[t*C2 + 64 + p] = xi;
            }
        }
        __syncthreads();
        #pragma unroll
        for (int i = 0; i < 16; i++){
            int idx = i*256 + tid;             // packed-pair index over 64x128
            int r = idx >> 6, cp = idx & 63;
            float v0 = smem[r*C2 + cp*2];
            float v1 = smem[r*C2 + cp*2 + 1];
            uint32_t pk = (uint32_t)f2bf(v0) | ((uint32_t)f2bf(v1) << 16);
            xl32[(size_t)(t0 + hr0 + r)*64 + cp] = pk;
        }
    }
    if (tid == 0) ((int*)(wsf + FR_OFF))[cc] = fr_sh;
}

// ---------------- K2: scan over chunk aggregates -> x_in per chunk ----------------
__global__ void k2(const float* __restrict__ x0re, const float* __restrict__ x0im,
                   float* __restrict__ wsf){
    const int p = threadIdx.x;                 // 64 threads
    const uint16_t* xl = (const uint16_t*)(wsf + XL_OFF);
    const int* frg = (const int*)(wsf + FR_OFF);
    const float ltr = wsf[LPRE_OFF + 127*64 + p];   // lambda^128
    const float lti = wsf[LPIM_OFF + 127*64 + p];
    float xr = x0re[p], xi = x0im[p];
    const int G = 16;
    float br[G], bi[G], br2[G], bi2[G]; int fr[G], fr2[G];

    auto ldg = [&](int cb, float* brb, float* bib, int* frb){
        #pragma unroll
        for (int j = 0; j < G; j++){
            const uint16_t* row = xl + (size_t)((cb + j)*T_CH + T_CH - 1) * C2;
            brb[j] = bf2f(row[p]);
            bib[j] = bf2f(row[64 + p]);
            frb[j] = frg[cb + j];
        }
    };
    ldg(0, br, bi, fr);
    for (int g = 0; g < NC / G; g++){
        int cb = g * G;
        if (g + 1 < NC / G) ldg(cb + G, br2, bi2, fr2);
        #pragma unroll
        for (int j = 0; j < G; j++){
            wsf[XIN_OFF + (cb + j)*C2 + p]      = xr;
            wsf[XIN_OFF + (cb + j)*C2 + 64 + p] = xi;
            if (fr[j] < T_CH){ xr = br[j]; xi = bi[j]; }
            else {
                float nr = fmaf(ltr, xr, fmaf(-lti, xi, br[j]));
                float ni = fmaf(ltr, xi, fmaf( lti, xr, bi[j]));
                xr = nr; xi = ni;
            }
        }
        #pragma unroll
        for (int j = 0; j < G; j++){ br[j]=br2[j]; bi[j]=bi2[j]; fr[j]=fr2[j]; }
    }
}

// ---------------- K3: corrected GEMM2 + epilogue -> y ----------------
__global__ __launch_bounds__(256) void k3(const float* __restrict__ u,
                                          const float* __restrict__ D,
                                          const float* __restrict__ wsf,
                                          float* __restrict__ y){
    __shared__ float a_lds[128*32];
    __shared__ float w_lds[32*128];
    const int tid = threadIdx.x;
    const int cc = blockIdx.x >> 1, hg = blockIdx.x & 1;
    const int t0 = cc * T_CH, h0 = hg * 128;
    const int ty = tid >> 4, tx = tid & 15;
    const int r0 = ty * 8, c0 = tx * 8;
    const uint16_t* xl = (const uint16_t*)(wsf + XL_OFF);
    const int fr = ((const int*)(wsf + FR_OFF))[cc];

    float acc[8][8] = {};

    for (int ks = 0; ks < 4; ks++){
        const int k0 = ks * 32;
        const bool imhalf = (k0 >= 64);
        __syncthreads();
        #pragma unroll
        for (int i = 0; i < 4; i++){
            int f = tid + i*256;
            int r = f >> 3, q = f & 7;
            int c = k0 + q*4;
            const uint16_t* src = xl + (size_t)(t0 + r)*C2 + c;
            uint2 pk = *(const uint2*)src;
            float v0 = bf2f((uint16_t)(pk.x & 0xffff));
            float v1 = bf2f((uint16_t)(pk.x >> 16));
            float v2 = bf2f((uint16_t)(pk.y & 0xffff));
            float v3 = bf2f((uint16_t)(pk.y >> 16));
            if (r < fr){
                int p = c & 63;
                float4 lr4 = *(const float4*)(wsf + LPRE_OFF + r*64 + p);
                float4 li4 = *(const float4*)(wsf + LPIM_OFF + r*64 + p);
                float4 xr4 = *(const float4*)(wsf + XIN_OFF + cc*C2 + p);
                float4 xi4 = *(const float4*)(wsf + XIN_OFF + cc*C2 + 64 + p);
                if (!imhalf){
                    v0 += lr4.x*xr4.x - li4.x*xi4.x;
                    v1 += lr4.y*xr4.y - li4.y*xi4.y;
                    v2 += lr4.z*xr4.z - li4.z*xi4.z;
                    v3 += lr4.w*xr4.w - li4.w*xi4.w;
                } else {
                    v0 += lr4.x*xi4.x + li4.x*xr4.x;
                    v1 += lr4.y*xi4.y + li4.y*xr4.y;
                    v2 += lr4.z*xi4.z + li4.z*xr4.z;
                    v3 += lr4.w*xi4.w + li4.w*xr4.w;
                }
            }
            float4 st = {v0, v1, v2, v3};
            *(float4*)(a_lds + r*32 + q*4) = st;
        }
        #pragma unroll
        for (int i = 0; i < 4; i++){
            int f = tid + i*256;
            int kk = f >> 5, q = f & 31;
            float4 v = *(const float4*)(wsf + W2_OFF + (k0 + kk)*H_DIM + h0 + q*4);
            *(float4*)(w_lds + kk*C2 + q*4) = v;
        }
        __syncthreads();
        #pragma unroll 4
        for (int k = 0; k < 32; k++){
            float a[8];
            #pragma unroll
            for (int i = 0; i < 8; i++) a[i] = a_lds[(r0 + i)*32 + k];
            float4 w0 = *(const float4*)(w_lds + k*C2 + c0);
            float4 w1 = *(const float4*)(w_lds + k*C2 + c0 + 4);
            float w[8] = {w0.x, w0.y, w0.z, w0.w, w1.x, w1.y, w1.z, w1.w};
            #pragma unroll
            for (int i = 0; i < 8; i++)
                #pragma unroll
                for (int j = 0; j < 8; j++)
                    acc[i][j] = fmaf(a[i], w[j], acc[i][j]);
        }
    }

    float4 d0 = *(const float4*)(D + h0 + c0);
    float4 d1 = *(const float4*)(D + h0 + c0 + 4);
    float dv[8] = {d0.x, d0.y, d0.z, d0.w, d1.x, d1.y, d1.z, d1.w};
    #pragma unroll
    for (int i = 0; i < 8; i++){
        const float* urow = u + (size_t)(t0 + r0 + i)*H_DIM + h0 + c0;
        float4 u0 = *(const float4*)(urow);
        float4 u1 = *(const float4*)(urow + 4);
        float uv[8] = {u0.x, u0.y, u0.z, u0.w, u1.x, u1.y, u1.z, u1.w};
        float4 o0, o1;
        o0.x = fmaf(uv[0], dv[0], acc[i][0]);
        o0.y = fmaf(uv[1], dv[1], acc[i][1]);
        o0.z = fmaf(uv[2], dv[2], acc[i][2]);
        o0.w = fmaf(uv[3], dv[3], acc[i][3]);
        o1.x = fmaf(uv[4], dv[4], acc[i][4]);
        o1.y = fmaf(uv[5], dv[5], acc[i][5]);
        o1.z = fmaf(uv[6], dv[6], acc[i][6]);
        o1.w = fmaf(uv[7], dv[7], acc[i][7]);
        float* yrow = y + (size_t)(t0 + r0 + i)*H_DIM + h0 + c0;
        *(float4*)yrow = o0;
        *(float4*)(yrow + 4) = o1;
    }
}

extern "C" void kernel_launch(void* const* d_in, const int* in_sizes, int n_in,
                              void* d_out, int out_size, void* d_ws, size_t ws_size,
                              hipStream_t stream){
    const float* u      = (const float*)d_in[0];
    const float* Lre    = (const float*)d_in[1];
    const float* Lim    = (const float*)d_in[2];
    const float* Bre    = (const float*)d_in[3];
    const float* Bim    = (const float*)d_in[4];
    const float* Cre    = (const float*)d_in[5];
    const float* Cim    = (const float*)d_in[6];
    const float* D      = (const float*)d_in[7];
    const float* deltas = (const float*)d_in[8];
    const float* x0re   = (const float*)d_in[9];
    const float* x0im   = (const float*)d_in[10];
    const int*   dflag  = (const int*)d_in[11];
    float* wsf = (float*)d_ws;
    float* y   = (float*)d_out;

    k0a<<<1, 64, 0, stream>>>(Lre, Lim, deltas, wsf);
    k0b<<<256, 256, 0, stream>>>(Bre, Bim, Cre, Cim, wsf);
    k1<<<NC, 256, 0, stream>>>(u, dflag, wsf);
    k2<<<1, 64, 0, stream>>>(x0re, x0im, wsf);
    k3<<<NC*2, 256, 0, stream>>>(u, D, wsf, y);
}

// Round 3
// 463.075 us; speedup vs baseline: 1.1726x; 1.1726x over previous
//
#include <hip/hip_runtime.h>
#include <hip/hip_bf16.h>
#include <stdint.h>

#define L_SEQ 131072
#define H_DIM 256
#define P_DIM 64
#define C2    128      // 2*P (re|im)
#define T_CH  128      // chunk length
#define NC    1024     // chunks
#define SUBT  32       // sub-chunk length (per wave)
#define BPAD  136      // padded row of x/Bu LDS buffer (bf16 elements)

typedef unsigned short u16t;
typedef __attribute__((ext_vector_type(8))) short short8;
typedef __attribute__((ext_vector_type(4))) float f32x4;

// ---- workspace map (byte offsets) ----
// W1bf  u16 [128 c][256 h]   @ 0        (65536 B)
// W2bf  u16 [256 h][128 c]   @ 65536    (65536 B)
// LPRE  f32 [128][64]        @ 131072   lambda^(k+1) re
// LPIM  f32 [128][64]        @ 163840
// LAMB  f32 [256]            @ 196608   lbr|lbi|gr|gi
// FR    int [NC]             @ 197632
// CLAST f32 [NC][128]        @ 201728
// XIN   f32 [NC][128]        @ 726016
// U16   u16 [L][256]         @ 2097152  (67108864 B)
#define OFF_W2_U   32768u
#define OFF_LPRE_F 32768u
#define OFF_LPIM_F 40960u
#define OFF_LAMB_F 49152u
#define OFF_FR_I   49408u
#define OFF_CL_F   50432u
#define OFF_XIN_F  181504u
#define OFF_U16_B  2097152u

__device__ __forceinline__ float bf2f(unsigned v){
    return __builtin_bit_cast(float, v << 16);
}
// round-to-nearest-even f32 -> bf16 (inputs are finite; no NaN handling needed)
__device__ __forceinline__ u16t f2bf16(float f){
    uint32_t u = __builtin_bit_cast(uint32_t, f);
    u += 0x7fffu + ((u >> 16) & 1u);
    return (u16t)(u >> 16);
}
__device__ __forceinline__ unsigned pk2(float a, float b){
    return (unsigned)f2bf16(a) | ((unsigned)f2bf16(b) << 16);
}

// ---------------- k0a: lambda_bar, g, power table ----------------
__global__ void k0a(const float* __restrict__ Lre, const float* __restrict__ Lim,
                    const float* __restrict__ deltas, float* __restrict__ wsf){
    int p = threadIdx.x;
    if (p >= P_DIM) return;
    float lr = Lre[p], li = Lim[p], dl = deltas[p];
    float er = expf(lr * dl);
    float si, co;
    sincosf(li * dl, &si, &co);
    float lbr = er * co, lbi = er * si;
    float den = lr*lr + li*li;
    float gr = ((lbr - 1.f)*lr + lbi*li) / den;
    float gi = (lbi*lr - (lbr - 1.f)*li) / den;
    float* lamb = wsf + OFF_LAMB_F;
    lamb[p] = lbr; lamb[64+p] = lbi; lamb[128+p] = gr; lamb[192+p] = gi;
    float* lpre = wsf + OFF_LPRE_F;
    float* lpim = wsf + OFF_LPIM_F;
    float pr = lbr, pi = lbi;
    for (int k = 0; k < T_CH; k++){
        lpre[k*64 + p] = pr;
        lpim[k*64 + p] = pi;
        float nr = pr*lbr - pi*lbi;
        float ni = pr*lbi + pi*lbr;
        pr = nr; pi = ni;
    }
}

// ---------------- k0b: bf16 weight build ----------------
__global__ void k0b(const float* __restrict__ Bre, const float* __restrict__ Bim,
                    const float* __restrict__ Cre, const float* __restrict__ Cim,
                    float* __restrict__ wsf, u16t* __restrict__ wsu){
    int idx = blockIdx.x * 256 + threadIdx.x;
    const float* lamb = wsf + OFF_LAMB_F;
    if (idx < 32768){
        int c = idx >> 8, h = idx & 255;      // W1[c][h]
        int p = c & 63;
        float gr = lamb[128+p], gi = lamb[192+p];
        float br = Bre[p*H_DIM + h], bi = Bim[p*H_DIM + h];
        float v = (c < 64) ? (gr*br - gi*bi) : (gr*bi + gi*br);
        wsu[idx] = f2bf16(v);
    } else {
        int i2 = idx - 32768;
        int h = i2 >> 7, c = i2 & 127;        // W2[h][c]
        float v = (c < 64) ? 2.f * Cre[h*P_DIM + c] : -2.f * Cim[h*P_DIM + (c-64)];
        wsu[OFF_W2_U + i2] = f2bf16(v);
    }
}

// ---------------- k1: GEMM1 (MFMA) + sub-chunk scan -> chunk_last, fr, u16 ----------------
template<bool WRITE_U16>
__global__ __launch_bounds__(256, 2) void k1(const float* __restrict__ u,
                                             const int* __restrict__ dflag,
                                             float* __restrict__ wsf,
                                             u16t* __restrict__ wsu,
                                             u16t* __restrict__ u16g){
    __shared__ u16t  buf[T_CH * BPAD];
    __shared__ int   d_lds[T_CH];
    __shared__ float sublast[4*128];
    __shared__ int   sfr[4];

    const int tid  = threadIdx.x;
    const int w    = tid >> 6, lane = tid & 63;
    const int m    = lane & 15, q = lane >> 4;
    const int cc   = blockIdx.x;
    const int t0   = cc * T_CH;
    const int tg   = t0 + w * SUBT;            // wave t base (global)

    if (tid < T_CH) d_lds[tid] = dflag[t0 + tid];

    const u16t* W1 = wsu;
    f32x4 acc[2][8];
    #pragma unroll
    for (int a = 0; a < 2; a++)
        #pragma unroll
        for (int b = 0; b < 8; b++) acc[a][b] = (f32x4){0.f,0.f,0.f,0.f};

    #pragma unroll
    for (int kf = 0; kf < 8; kf++){
        const int k0 = kf*32 + q*8;
        short8 afr[2];
        #pragma unroll
        for (int mt = 0; mt < 2; mt++){
            const float* ap = u + (size_t)(tg + mt*16 + m)*H_DIM + k0;
            float4 f0 = *(const float4*)ap;
            float4 f1 = *(const float4*)(ap + 4);
            uint4 pk;
            pk.x = pk2(f0.x, f0.y); pk.y = pk2(f0.z, f0.w);
            pk.z = pk2(f1.x, f1.y); pk.w = pk2(f1.z, f1.w);
            if (WRITE_U16)
                *(uint4*)(u16g + (size_t)(tg + mt*16 + m)*H_DIM + k0) = pk;
            afr[mt] = __builtin_bit_cast(short8, pk);
        }
        #pragma unroll
        for (int nt = 0; nt < 8; nt++){
            short8 bfr = __builtin_bit_cast(short8, *(const uint4*)(W1 + (nt*16 + m)*H_DIM + k0));
            acc[0][nt] = __builtin_amdgcn_mfma_f32_16x16x32_bf16(afr[0], bfr, acc[0][nt], 0,0,0);
            acc[1][nt] = __builtin_amdgcn_mfma_f32_16x16x32_bf16(afr[1], bfr, acc[1][nt], 0,0,0);
        }
    }
    // Bu -> LDS (bf16)   D layout: col=lane&15, row=quad*4+reg
    #pragma unroll
    for (int mt = 0; mt < 2; mt++)
        #pragma unroll
        for (int nt = 0; nt < 8; nt++){
            int c  = nt*16 + m;
            int tl = w*SUBT + mt*16 + q*4;
            #pragma unroll
            for (int r = 0; r < 4; r++)
                buf[(tl + r)*BPAD + c] = f2bf16(acc[mt][nt][r]);
        }
    __syncthreads();

    // sub-chunk scan: wave w handles tl in [w*32, w*32+32)
    {
        const float* lamb = wsf + OFF_LAMB_F;
        float lbr = lamb[lane], lbi = lamb[64 + lane];
        float xr = 0.f, xi = 0.f;
        int frs = SUBT;
        const int base = w * SUBT;
        for (int tt = 0; tt < SUBT; tt++){
            int tl = base + tt;
            float br = bf2f(buf[tl*BPAD + lane]);
            float bi = bf2f(buf[tl*BPAD + 64 + lane]);
            if (d_lds[tl]){
                if (frs == SUBT) frs = tt;
                xr = br; xi = bi;
            } else {
                float nr = fmaf(lbr, xr, fmaf(-lbi, xi, br));
                float ni = fmaf(lbr, xi, fmaf( lbi, xr, bi));
                xr = nr; xi = ni;
            }
        }
        sublast[w*128 + lane]      = xr;
        sublast[w*128 + 64 + lane] = xi;
        if (lane == 0) sfr[w] = frs;
    }
    __syncthreads();

    if (tid < 64){
        const float* lpre = wsf + OFF_LPRE_F;
        const float* lpim = wsf + OFF_LPIM_F;
        float l32r = lpre[(SUBT-1)*64 + tid], l32i = lpim[(SUBT-1)*64 + tid];
        float xr = 0.f, xi = 0.f;
        int fr_c = T_CH;
        #pragma unroll
        for (int w2 = 0; w2 < 4; w2++){
            float sr = sublast[w2*128 + tid], si = sublast[w2*128 + 64 + tid];
            int f = sfr[w2];
            if (f < SUBT){
                xr = sr; xi = si;
                if (fr_c == T_CH) fr_c = w2*SUBT + f;
            } else {
                float nr = fmaf(l32r, xr, fmaf(-l32i, xi, sr));
                float ni = fmaf(l32r, xi, fmaf( l32i, xr, si));
                xr = nr; xi = ni;
            }
        }
        float* clast = wsf + OFF_CL_F;
        clast[cc*128 + tid]      = xr;
        clast[cc*128 + 64 + tid] = xi;
        if (tid == 0) ((int*)wsf)[OFF_FR_I + cc] = fr_c;
    }
}

// ---------------- k2: serial scan over chunk aggregates ----------------
__global__ void k2(const float* __restrict__ x0re, const float* __restrict__ x0im,
                   float* __restrict__ wsf){
    const int p = threadIdx.x;            // 64 threads
    const float* clast = wsf + OFF_CL_F;
    const int*   frg   = (const int*)wsf + OFF_FR_I;
    float*       xin   = wsf + OFF_XIN_F;
    const float ltr = (wsf + OFF_LPRE_F)[127*64 + p];  // lambda^128
    const float lti = (wsf + OFF_LPIM_F)[127*64 + p];
    float xr = x0re[p], xi = x0im[p];
    const int G = 16;
    float br[G], bi[G], br2[G], bi2[G]; int fr[G], fr2[G];

    auto ldg = [&](int cb, float* A, float* B, int* F){
        #pragma unroll
        for (int j = 0; j < G; j++){
            A[j] = clast[(cb+j)*128 + p];
            B[j] = clast[(cb+j)*128 + 64 + p];
            F[j] = frg[cb+j];
        }
    };
    ldg(0, br, bi, fr);
    for (int g = 0; g < NC / G; g++){
        int cb = g * G;
        if (g + 1 < NC / G) ldg(cb + G, br2, bi2, fr2);
        #pragma unroll
        for (int j = 0; j < G; j++){
            xin[(cb+j)*128 + p]      = xr;
            xin[(cb+j)*128 + 64 + p] = xi;
            if (fr[j] < T_CH){ xr = br[j]; xi = bi[j]; }
            else {
                float nr = fmaf(ltr, xr, fmaf(-lti, xi, br[j]));
                float ni = fmaf(ltr, xi, fmaf( lti, xr, bi[j]));
                xr = nr; xi = ni;
            }
        }
        #pragma unroll
        for (int j = 0; j < G; j++){ br[j]=br2[j]; bi[j]=bi2[j]; fr[j]=fr2[j]; }
    }
}

// ---------------- k3: recompute GEMM1+scan, correct, GEMM2 + epilogue -> y ----------------
template<bool USE_U16>
__global__ __launch_bounds__(256, 2) void k3(const float* __restrict__ u,
                                             const u16t* __restrict__ u16g,
                                             const int* __restrict__ dflag,
                                             const float* __restrict__ D,
                                             float* __restrict__ wsf,
                                             u16t* __restrict__ wsu,
                                             float* __restrict__ y){
    __shared__ u16t  buf[T_CH * BPAD];
    __shared__ int   d_lds[T_CH];
    __shared__ float sublast[4*128];
    __shared__ float xin_s[4*128];
    __shared__ int   sfr[4];

    const int tid  = threadIdx.x;
    const int w    = tid >> 6, lane = tid & 63;
    const int m    = lane & 15, q = lane >> 4;
    const int cc   = blockIdx.x;
    const int t0   = cc * T_CH;
    const int tg   = t0 + w * SUBT;

    if (tid < T_CH) d_lds[tid] = dflag[t0 + tid];

    // ---- Phase A: GEMM1 ----
    {
        const u16t* W1 = wsu;
        f32x4 acc[2][8];
        #pragma unroll
        for (int a = 0; a < 2; a++)
            #pragma unroll
            for (int b = 0; b < 8; b++) acc[a][b] = (f32x4){0.f,0.f,0.f,0.f};

        #pragma unroll
        for (int kf = 0; kf < 8; kf++){
            const int k0 = kf*32 + q*8;
            short8 afr[2];
            #pragma unroll
            for (int mt = 0; mt < 2; mt++){
                if (USE_U16){
                    afr[mt] = __builtin_bit_cast(short8,
                        *(const uint4*)(u16g + (size_t)(tg + mt*16 + m)*H_DIM + k0));
                } else {
                    const float* ap = u + (size_t)(tg + mt*16 + m)*H_DIM + k0;
                    float4 f0 = *(const float4*)ap;
                    float4 f1 = *(const float4*)(ap + 4);
                    uint4 pk;
                    pk.x = pk2(f0.x, f0.y); pk.y = pk2(f0.z, f0.w);
                    pk.z = pk2(f1.x, f1.y); pk.w = pk2(f1.z, f1.w);
                    afr[mt] = __builtin_bit_cast(short8, pk);
                }
            }
            #pragma unroll
            for (int nt = 0; nt < 8; nt++){
                short8 bfr = __builtin_bit_cast(short8, *(const uint4*)(W1 + (nt*16 + m)*H_DIM + k0));
                acc[0][nt] = __builtin_amdgcn_mfma_f32_16x16x32_bf16(afr[0], bfr, acc[0][nt], 0,0,0);
                acc[1][nt] = __builtin_amdgcn_mfma_f32_16x16x32_bf16(afr[1], bfr, acc[1][nt], 0,0,0);
            }
        }
        #pragma unroll
        for (int mt = 0; mt < 2; mt++)
            #pragma unroll
            for (int nt = 0; nt < 8; nt++){
                int c  = nt*16 + m;
                int tl = w*SUBT + mt*16 + q*4;
                #pragma unroll
                for (int r = 0; r < 4; r++)
                    buf[(tl + r)*BPAD + c] = f2bf16(acc[mt][nt][r]);
            }
    }
    __syncthreads();

    // ---- Phase B: sub-chunk scan with writeback ----
    {
        const float* lamb = wsf + OFF_LAMB_F;
        float lbr = lamb[lane], lbi = lamb[64 + lane];
        float xr = 0.f, xi = 0.f;
        int frs = SUBT;
        const int base = w * SUBT;
        for (int tt = 0; tt < SUBT; tt++){
            int tl = base + tt;
            float br = bf2f(buf[tl*BPAD + lane]);
            float bi = bf2f(buf[tl*BPAD + 64 + lane]);
            if (d_lds[tl]){
                if (frs == SUBT) frs = tt;
                xr = br; xi = bi;
            } else {
                float nr = fmaf(lbr, xr, fmaf(-lbi, xi, br));
                float ni = fmaf(lbr, xi, fmaf( lbi, xr, bi));
                xr = nr; xi = ni;
            }
            buf[tl*BPAD + lane]      = f2bf16(xr);
            buf[tl*BPAD + 64 + lane] = f2bf16(xi);
        }
        sublast[w*128 + lane]      = xr;
        sublast[w*128 + 64 + lane] = xi;
        if (lane == 0) sfr[w] = frs;
    }
    __syncthreads();

    // ---- Phase C: incoming state per sub-chunk ----
    if (tid < 64){
        const float* lpre = wsf + OFF_LPRE_F;
        const float* lpim = wsf + OFF_LPIM_F;
        const float* xin  = wsf + OFF_XIN_F;
        float l32r = lpre[(SUBT-1)*64 + tid], l32i = lpim[(SUBT-1)*64 + tid];
        float xr = xin[cc*128 + tid], xi = xin[cc*128 + 64 + tid];
        #pragma unroll
        for (int w2 = 0; w2 < 4; w2++){
            xin_s[w2*128 + tid]      = xr;
            xin_s[w2*128 + 64 + tid] = xi;
            float sr = sublast[w2*128 + tid], si = sublast[w2*128 + 64 + tid];
            if (sfr[w2] < SUBT){ xr = sr; xi = si; }
            else {
                float nr = fmaf(l32r, xr, fmaf(-l32i, xi, sr));
                float ni = fmaf(l32r, xi, fmaf( l32i, xr, si));
                xr = nr; xi = ni;
            }
        }
    }
    __syncthreads();

    // ---- Phase D: correction x += lambda^(tt+1) * x_in_sub (rows before sub first-reset) ----
    {
        const float* lpre = wsf + OFF_LPRE_F;
        const float* lpim = wsf + OFF_LPIM_F;
        #pragma unroll 4
        for (int i = 0; i < 32; i++){
            int idx = i*256 + tid;           // pair index over 128 x 64 pairs
            int tl = idx >> 6, j = idx & 63;
            int c0 = j*2;
            int w2 = tl >> 5, tt = tl & 31;
            if (tt < sfr[w2]){
                unsigned pr = *(unsigned*)&buf[tl*BPAD + c0];
                float v0 = bf2f(pr & 0xffffu), v1 = bf2f(pr >> 16);
                int p0 = c0 & 63;
                float lr0 = lpre[tt*64 + p0], lr1 = lpre[tt*64 + p0 + 1];
                float li0 = lpim[tt*64 + p0], li1 = lpim[tt*64 + p0 + 1];
                float xr0 = xin_s[w2*128 + p0],      xr1 = xin_s[w2*128 + p0 + 1];
                float xi0 = xin_s[w2*128 + 64 + p0], xi1 = xin_s[w2*128 + 64 + p0 + 1];
                if (c0 < 64){
                    v0 += lr0*xr0 - li0*xi0;
                    v1 += lr1*xr1 - li1*xi1;
                } else {
                    v0 += lr0*xi0 + li0*xr0;
                    v1 += lr1*xi1 + li1*xr1;
                }
                *(unsigned*)&buf[tl*BPAD + c0] = pk2(v0, v1);
            }
        }
    }
    __syncthreads();

    // ---- Phase E: GEMM2  y[t][h] = X[t][c] * W2[h][c] ----
    f32x4 acc2[2][16];
    #pragma unroll
    for (int a = 0; a < 2; a++)
        #pragma unroll
        for (int b = 0; b < 16; b++) acc2[a][b] = (f32x4){0.f,0.f,0.f,0.f};
    {
        const u16t* W2 = wsu + OFF_W2_U;
        #pragma unroll
        for (int ng = 0; ng < 4; ng++){
            #pragma unroll
            for (int kf = 0; kf < 4; kf++){
                const int k0 = kf*32 + q*8;
                short8 a0 = *(const short8*)&buf[(w*SUBT +  0 + m)*BPAD + k0];
                short8 a1 = *(const short8*)&buf[(w*SUBT + 16 + m)*BPAD + k0];
                #pragma unroll
                for (int nj = 0; nj < 4; nj++){
                    int nt = ng*4 + nj;
                    short8 bfr = __builtin_bit_cast(short8, *(const uint4*)(W2 + (nt*16 + m)*C2 + k0));
                    acc2[0][nt] = __builtin_amdgcn_mfma_f32_16x16x32_bf16(a0, bfr, acc2[0][nt], 0,0,0);
                    acc2[1][nt] = __builtin_amdgcn_mfma_f32_16x16x32_bf16(a1, bfr, acc2[1][nt], 0,0,0);
                }
            }
        }
    }

    // ---- Phase F: epilogue  y = acc2 + u*D ----
    #pragma unroll
    for (int nt = 0; nt < 16; nt++){
        int h = nt*16 + m;
        float dv = D[h];
        #pragma unroll
        for (int mt = 0; mt < 2; mt++){
            int tb = tg + mt*16 + q*4;
            #pragma unroll
            for (int r = 0; r < 4; r++){
                float uv = USE_U16 ? bf2f(u16g[(size_t)(tb + r)*H_DIM + h])
                                   : u[(size_t)(tb + r)*H_DIM + h];
                y[(size_t)(tb + r)*H_DIM + h] = fmaf(uv, dv, acc2[mt][nt][r]);
            }
        }
    }
}

extern "C" void kernel_launch(void* const* d_in, const int* in_sizes, int n_in,
                              void* d_out, int out_size, void* d_ws, size_t ws_size,
                              hipStream_t stream){
    const float* u      = (const float*)d_in[0];
    const float* Lre    = (const float*)d_in[1];
    const float* Lim    = (const float*)d_in[2];
    const float* Bre    = (const float*)d_in[3];
    const float* Bim    = (const float*)d_in[4];
    const float* Cre    = (const float*)d_in[5];
    const float* Cim    = (const float*)d_in[6];
    const float* D      = (const float*)d_in[7];
    const float* x0re   = (const float*)d_in[9];
    const float* x0im   = (const float*)d_in[10];
    const int*   dflag  = (const int*)d_in[11];
    const float* deltas = (const float*)d_in[8];
    float* wsf = (float*)d_ws;
    u16t*  wsu = (u16t*)d_ws;
    u16t*  u16g = (u16t*)((char*)d_ws + OFF_U16_B);
    float* y   = (float*)d_out;

    const size_t need = (size_t)OFF_U16_B + (size_t)L_SEQ * H_DIM * 2;
    const bool use16 = (ws_size >= need);

    k0a<<<1, 64, 0, stream>>>(Lre, Lim, deltas, wsf);
    k0b<<<256, 256, 0, stream>>>(Bre, Bim, Cre, Cim, wsf, wsu);
    if (use16){
        k1<true ><<<NC, 256, 0, stream>>>(u, dflag, wsf, wsu, u16g);
        k2<<<1, 64, 0, stream>>>(x0re, x0im, wsf);
        k3<true ><<<NC, 256, 0, stream>>>(u, u16g, dflag, D, wsf, wsu, y);
    } else {
        k1<false><<<NC, 256, 0, stream>>>(u, dflag, wsf, wsu, u16g);
        k2<<<1, 64, 0, stream>>>(x0re, x0im, wsf);
        k3<false><<<NC, 256, 0, stream>>>(u, u16g, dflag, D, wsf, wsu, y);
    }
}

// Round 4
// 456.192 us; speedup vs baseline: 1.1903x; 1.0151x over previous
//
#include <hip/hip_runtime.h>
#include <hip/hip_bf16.h>
#include <stdint.h>

#define L_SEQ 131072
#define H_DIM 256
#define P_DIM 64
#define C2    128      // 2*P (re|im)
#define T_CH  128      // chunk length
#define NC    1024     // chunks
#define SUBT  32       // sub-chunk length (per wave)
#define BPAD  136      // padded row of x/Bu LDS buffer (bf16 elements)

typedef unsigned short u16t;
typedef __attribute__((ext_vector_type(8))) short short8;
typedef __attribute__((ext_vector_type(4))) float f32x4;

// ---- workspace map (byte offsets) ----
// W1bf  u16 [128 c][256 h]   @ 0        (65536 B)
// W2bf  u16 [256 h][128 c]   @ 65536    (65536 B)
// LPRE  f32 [128][64]        @ 131072   lambda^(k+1) re
// LPIM  f32 [128][64]        @ 163840
// LAMB  f32 [256]            @ 196608   lbr|lbi|gr|gi
// FR    int [NC]             @ 197632
// CLAST f32 [NC][128]        @ 201728
// XIN   f32 [NC][128]        @ 726016
// U16   u16 [L][256]         @ 2097152  (67108864 B)
#define OFF_W2_U   32768u
#define OFF_LPRE_F 32768u
#define OFF_LPIM_F 40960u
#define OFF_LAMB_F 49152u
#define OFF_FR_I   49408u
#define OFF_CL_F   50432u
#define OFF_XIN_F  181504u
#define OFF_U16_B  2097152u

__device__ __forceinline__ float bf2f(unsigned v){
    return __builtin_bit_cast(float, v << 16);
}
// round-to-nearest-even f32 -> bf16 (inputs are finite; no NaN handling needed)
__device__ __forceinline__ u16t f2bf16(float f){
    uint32_t u = __builtin_bit_cast(uint32_t, f);
    u += 0x7fffu + ((u >> 16) & 1u);
    return (u16t)(u >> 16);
}
__device__ __forceinline__ unsigned pk2(float a, float b){
    return (unsigned)f2bf16(a) | ((unsigned)f2bf16(b) << 16);
}

// ---------------- kconv: u fp32 -> bf16 (pure streaming, coalesced) ----------------
__global__ __launch_bounds__(256) void kconv(const float* __restrict__ u,
                                             u16t* __restrict__ o){
    const size_t n = (size_t)L_SEQ * H_DIM / 8;
    size_t i = (size_t)blockIdx.x * 256 + threadIdx.x;
    const size_t step = (size_t)gridDim.x * 256;
    for (; i < n; i += step){
        const float* p = u + i*8;
        float4 a = *(const float4*)p;
        float4 b = *(const float4*)(p + 4);
        uint4 o4;
        o4.x = pk2(a.x, a.y); o4.y = pk2(a.z, a.w);
        o4.z = pk2(b.x, b.y); o4.w = pk2(b.z, b.w);
        *(uint4*)(o + i*8) = o4;
    }
}

// ---------------- k0a: lambda_bar, g, power table ----------------
__global__ void k0a(const float* __restrict__ Lre, const float* __restrict__ Lim,
                    const float* __restrict__ deltas, float* __restrict__ wsf){
    int p = threadIdx.x;
    if (p >= P_DIM) return;
    float lr = Lre[p], li = Lim[p], dl = deltas[p];
    float er = expf(lr * dl);
    float si, co;
    sincosf(li * dl, &si, &co);
    float lbr = er * co, lbi = er * si;
    float den = lr*lr + li*li;
    float gr = ((lbr - 1.f)*lr + lbi*li) / den;
    float gi = (lbi*lr - (lbr - 1.f)*li) / den;
    float* lamb = wsf + OFF_LAMB_F;
    lamb[p] = lbr; lamb[64+p] = lbi; lamb[128+p] = gr; lamb[192+p] = gi;
    float* lpre = wsf + OFF_LPRE_F;
    float* lpim = wsf + OFF_LPIM_F;
    float pr = lbr, pi = lbi;
    for (int k = 0; k < T_CH; k++){
        lpre[k*64 + p] = pr;
        lpim[k*64 + p] = pi;
        float nr = pr*lbr - pi*lbi;
        float ni = pr*lbi + pi*lbr;
        pr = nr; pi = ni;
    }
}

// ---------------- k0b: bf16 weight build ----------------
__global__ void k0b(const float* __restrict__ Bre, const float* __restrict__ Bim,
                    const float* __restrict__ Cre, const float* __restrict__ Cim,
                    float* __restrict__ wsf, u16t* __restrict__ wsu){
    int idx = blockIdx.x * 256 + threadIdx.x;
    const float* lamb = wsf + OFF_LAMB_F;
    if (idx < 32768){
        int c = idx >> 8, h = idx & 255;      // W1[c][h]
        int p = c & 63;
        float gr = lamb[128+p], gi = lamb[192+p];
        float br = Bre[p*H_DIM + h], bi = Bim[p*H_DIM + h];
        float v = (c < 64) ? (gr*br - gi*bi) : (gr*bi + gi*br);
        wsu[idx] = f2bf16(v);
    } else {
        int i2 = idx - 32768;
        int h = i2 >> 7, c = i2 & 127;        // W2[h][c]
        float v = (c < 64) ? 2.f * Cre[h*P_DIM + c] : -2.f * Cim[h*P_DIM + (c-64)];
        wsu[OFF_W2_U + i2] = f2bf16(v);
    }
}

// ---------------- k1: GEMM1 (MFMA) + sub-chunk scan -> chunk_last, fr ----------------
template<bool USE_U16>
__global__ __launch_bounds__(256, 3) void k1(const float* __restrict__ u,
                                             const u16t* __restrict__ u16g,
                                             const int* __restrict__ dflag,
                                             float* __restrict__ wsf,
                                             u16t* __restrict__ wsu){
    __shared__ u16t  buf[T_CH * BPAD];
    __shared__ int   d_lds[T_CH];
    __shared__ float sublast[4*128];
    __shared__ int   sfr[4];

    const int tid  = threadIdx.x;
    const int w    = tid >> 6, lane = tid & 63;
    const int m    = lane & 15, q = lane >> 4;
    const int cc   = blockIdx.x;
    const int t0   = cc * T_CH;
    const int tg   = t0 + w * SUBT;            // wave t base (global)

    if (tid < T_CH) d_lds[tid] = dflag[t0 + tid];

    // ---- preload ALL A-fragments (16 x uint4 in flight per wave) ----
    uint4 ap[16];
    #pragma unroll
    for (int kf = 0; kf < 8; kf++){
        #pragma unroll
        for (int mt = 0; mt < 2; mt++){
            if (USE_U16){
                ap[kf*2+mt] = *(const uint4*)(u16g + (size_t)(tg + mt*16 + m)*H_DIM + kf*32 + q*8);
            } else {
                const float* apn = u + (size_t)(tg + mt*16 + m)*H_DIM + kf*32 + q*8;
                float4 f0 = *(const float4*)apn;
                float4 f1 = *(const float4*)(apn + 4);
                uint4 pk;
                pk.x = pk2(f0.x, f0.y); pk.y = pk2(f0.z, f0.w);
                pk.z = pk2(f1.x, f1.y); pk.w = pk2(f1.z, f1.w);
                ap[kf*2+mt] = pk;
            }
        }
    }

    const u16t* W1 = wsu;
    f32x4 acc[2][8];
    #pragma unroll
    for (int a = 0; a < 2; a++)
        #pragma unroll
        for (int b = 0; b < 8; b++) acc[a][b] = (f32x4){0.f,0.f,0.f,0.f};

    #pragma unroll
    for (int kf = 0; kf < 8; kf++){
        const int k0 = kf*32 + q*8;
        short8 a0 = __builtin_bit_cast(short8, ap[kf*2+0]);
        short8 a1 = __builtin_bit_cast(short8, ap[kf*2+1]);
        #pragma unroll
        for (int nt = 0; nt < 8; nt++){
            short8 bfr = __builtin_bit_cast(short8, *(const uint4*)(W1 + (nt*16 + m)*H_DIM + k0));
            acc[0][nt] = __builtin_amdgcn_mfma_f32_16x16x32_bf16(a0, bfr, acc[0][nt], 0,0,0);
            acc[1][nt] = __builtin_amdgcn_mfma_f32_16x16x32_bf16(a1, bfr, acc[1][nt], 0,0,0);
        }
    }
    // Bu -> LDS (bf16)   D layout: col=lane&15, row=quad*4+reg
    #pragma unroll
    for (int mt = 0; mt < 2; mt++)
        #pragma unroll
        for (int nt = 0; nt < 8; nt++){
            int c  = nt*16 + m;
            int tl = w*SUBT + mt*16 + q*4;
            #pragma unroll
            for (int r = 0; r < 4; r++)
                buf[(tl + r)*BPAD + c] = f2bf16(acc[mt][nt][r]);
        }
    __syncthreads();

    // sub-chunk scan: wave w handles tl in [w*32, w*32+32)
    {
        const float* lamb = wsf + OFF_LAMB_F;
        float lbr = lamb[lane], lbi = lamb[64 + lane];
        float xr = 0.f, xi = 0.f;
        int frs = SUBT;
        const int base = w * SUBT;
        for (int tt = 0; tt < SUBT; tt++){
            int tl = base + tt;
            float br = bf2f(buf[tl*BPAD + lane]);
            float bi = bf2f(buf[tl*BPAD + 64 + lane]);
            if (d_lds[tl]){
                if (frs == SUBT) frs = tt;
                xr = br; xi = bi;
            } else {
                float nr = fmaf(lbr, xr, fmaf(-lbi, xi, br));
                float ni = fmaf(lbr, xi, fmaf( lbi, xr, bi));
                xr = nr; xi = ni;
            }
        }
        sublast[w*128 + lane]      = xr;
        sublast[w*128 + 64 + lane] = xi;
        if (lane == 0) sfr[w] = frs;
    }
    __syncthreads();

    if (tid < 64){
        const float* lpre = wsf + OFF_LPRE_F;
        const float* lpim = wsf + OFF_LPIM_F;
        float l32r = lpre[(SUBT-1)*64 + tid], l32i = lpim[(SUBT-1)*64 + tid];
        float xr = 0.f, xi = 0.f;
        int fr_c = T_CH;
        #pragma unroll
        for (int w2 = 0; w2 < 4; w2++){
            float sr = sublast[w2*128 + tid], si = sublast[w2*128 + 64 + tid];
            int f = sfr[w2];
            if (f < SUBT){
                xr = sr; xi = si;
                if (fr_c == T_CH) fr_c = w2*SUBT + f;
            } else {
                float nr = fmaf(l32r, xr, fmaf(-l32i, xi, sr));
                float ni = fmaf(l32r, xi, fmaf( l32i, xr, si));
                xr = nr; xi = ni;
            }
        }
        float* clast = wsf + OFF_CL_F;
        clast[cc*128 + tid]      = xr;
        clast[cc*128 + 64 + tid] = xi;
        if (tid == 0) ((int*)wsf)[OFF_FR_I + cc] = fr_c;
    }
}

// ---------------- k2: serial scan over chunk aggregates ----------------
__global__ void k2(const float* __restrict__ x0re, const float* __restrict__ x0im,
                   float* __restrict__ wsf){
    const int p = threadIdx.x;            // 64 threads
    const float* clast = wsf + OFF_CL_F;
    const int*   frg   = (const int*)wsf + OFF_FR_I;
    float*       xin   = wsf + OFF_XIN_F;
    const float ltr = (wsf + OFF_LPRE_F)[127*64 + p];  // lambda^128
    const float lti = (wsf + OFF_LPIM_F)[127*64 + p];
    float xr = x0re[p], xi = x0im[p];
    const int G = 16;
    float br[G], bi[G], br2[G], bi2[G]; int fr[G], fr2[G];

    auto ldg = [&](int cb, float* A, float* B, int* F){
        #pragma unroll
        for (int j = 0; j < G; j++){
            A[j] = clast[(cb+j)*128 + p];
            B[j] = clast[(cb+j)*128 + 64 + p];
            F[j] = frg[cb+j];
        }
    };
    ldg(0, br, bi, fr);
    for (int g = 0; g < NC / G; g++){
        int cb = g * G;
        if (g + 1 < NC / G) ldg(cb + G, br2, bi2, fr2);
        #pragma unroll
        for (int j = 0; j < G; j++){
            xin[(cb+j)*128 + p]      = xr;
            xin[(cb+j)*128 + 64 + p] = xi;
            if (fr[j] < T_CH){ xr = br[j]; xi = bi[j]; }
            else {
                float nr = fmaf(ltr, xr, fmaf(-lti, xi, br[j]));
                float ni = fmaf(ltr, xi, fmaf( lti, xr, bi[j]));
                xr = nr; xi = ni;
            }
        }
        #pragma unroll
        for (int j = 0; j < G; j++){ br[j]=br2[j]; bi[j]=bi2[j]; fr[j]=fr2[j]; }
    }
}

// ---------------- k3: recompute GEMM1+scan, correct, GEMM2 + epilogue -> y ----------------
template<bool USE_U16>
__global__ __launch_bounds__(256, 2) void k3(const float* __restrict__ u,
                                             const u16t* __restrict__ u16g,
                                             const int* __restrict__ dflag,
                                             const float* __restrict__ D,
                                             float* __restrict__ wsf,
                                             u16t* __restrict__ wsu,
                                             float* __restrict__ y){
    __shared__ u16t  buf[T_CH * BPAD];
    __shared__ int   d_lds[T_CH];
    __shared__ float sublast[4*128];
    __shared__ float xin_s[4*128];
    __shared__ int   sfr[4];

    const int tid  = threadIdx.x;
    const int w    = tid >> 6, lane = tid & 63;
    const int m    = lane & 15, q = lane >> 4;
    const int cc   = blockIdx.x;
    const int t0   = cc * T_CH;
    const int tg   = t0 + w * SUBT;

    if (tid < T_CH) d_lds[tid] = dflag[t0 + tid];

    // ---- Phase A: GEMM1 with full A-fragment preload ----
    {
        uint4 ap[16];
        #pragma unroll
        for (int kf = 0; kf < 8; kf++){
            #pragma unroll
            for (int mt = 0; mt < 2; mt++){
                if (USE_U16){
                    ap[kf*2+mt] = *(const uint4*)(u16g + (size_t)(tg + mt*16 + m)*H_DIM + kf*32 + q*8);
                } else {
                    const float* apn = u + (size_t)(tg + mt*16 + m)*H_DIM + kf*32 + q*8;
                    float4 f0 = *(const float4*)apn;
                    float4 f1 = *(const float4*)(apn + 4);
                    uint4 pk;
                    pk.x = pk2(f0.x, f0.y); pk.y = pk2(f0.z, f0.w);
                    pk.z = pk2(f1.x, f1.y); pk.w = pk2(f1.z, f1.w);
                    ap[kf*2+mt] = pk;
                }
            }
        }
        const u16t* W1 = wsu;
        f32x4 acc[2][8];
        #pragma unroll
        for (int a = 0; a < 2; a++)
            #pragma unroll
            for (int b = 0; b < 8; b++) acc[a][b] = (f32x4){0.f,0.f,0.f,0.f};

        #pragma unroll
        for (int kf = 0; kf < 8; kf++){
            const int k0 = kf*32 + q*8;
            short8 a0 = __builtin_bit_cast(short8, ap[kf*2+0]);
            short8 a1 = __builtin_bit_cast(short8, ap[kf*2+1]);
            #pragma unroll
            for (int nt = 0; nt < 8; nt++){
                short8 bfr = __builtin_bit_cast(short8, *(const uint4*)(W1 + (nt*16 + m)*H_DIM + k0));
                acc[0][nt] = __builtin_amdgcn_mfma_f32_16x16x32_bf16(a0, bfr, acc[0][nt], 0,0,0);
                acc[1][nt] = __builtin_amdgcn_mfma_f32_16x16x32_bf16(a1, bfr, acc[1][nt], 0,0,0);
            }
        }
        #pragma unroll
        for (int mt = 0; mt < 2; mt++)
            #pragma unroll
            for (int nt = 0; nt < 8; nt++){
                int c  = nt*16 + m;
                int tl = w*SUBT + mt*16 + q*4;
                #pragma unroll
                for (int r = 0; r < 4; r++)
                    buf[(tl + r)*BPAD + c] = f2bf16(acc[mt][nt][r]);
            }
    }
    __syncthreads();

    // ---- Phase B: sub-chunk scan with writeback ----
    {
        const float* lamb = wsf + OFF_LAMB_F;
        float lbr = lamb[lane], lbi = lamb[64 + lane];
        float xr = 0.f, xi = 0.f;
        int frs = SUBT;
        const int base = w * SUBT;
        for (int tt = 0; tt < SUBT; tt++){
            int tl = base + tt;
            float br = bf2f(buf[tl*BPAD + lane]);
            float bi = bf2f(buf[tl*BPAD + 64 + lane]);
            if (d_lds[tl]){
                if (frs == SUBT) frs = tt;
                xr = br; xi = bi;
            } else {
                float nr = fmaf(lbr, xr, fmaf(-lbi, xi, br));
                float ni = fmaf(lbr, xi, fmaf( lbi, xr, bi));
                xr = nr; xi = ni;
            }
            buf[tl*BPAD + lane]      = f2bf16(xr);
            buf[tl*BPAD + 64 + lane] = f2bf16(xi);
        }
        sublast[w*128 + lane]      = xr;
        sublast[w*128 + 64 + lane] = xi;
        if (lane == 0) sfr[w] = frs;
    }
    __syncthreads();

    // ---- Phase C: incoming state per sub-chunk ----
    if (tid < 64){
        const float* lpre = wsf + OFF_LPRE_F;
        const float* lpim = wsf + OFF_LPIM_F;
        const float* xin  = wsf + OFF_XIN_F;
        float l32r = lpre[(SUBT-1)*64 + tid], l32i = lpim[(SUBT-1)*64 + tid];
        float xr = xin[cc*128 + tid], xi = xin[cc*128 + 64 + tid];
        #pragma unroll
        for (int w2 = 0; w2 < 4; w2++){
            xin_s[w2*128 + tid]      = xr;
            xin_s[w2*128 + 64 + tid] = xi;
            float sr = sublast[w2*128 + tid], si = sublast[w2*128 + 64 + tid];
            if (sfr[w2] < SUBT){ xr = sr; xi = si; }
            else {
                float nr = fmaf(l32r, xr, fmaf(-l32i, xi, sr));
                float ni = fmaf(l32r, xi, fmaf( l32i, xr, si));
                xr = nr; xi = ni;
            }
        }
    }
    __syncthreads();

    // ---- Phase D: correction x += lambda^(tt+1) * x_in_sub (rows before sub first-reset) ----
    {
        const float* lpre = wsf + OFF_LPRE_F;
        const float* lpim = wsf + OFF_LPIM_F;
        #pragma unroll 4
        for (int i = 0; i < 32; i++){
            int idx = i*256 + tid;           // pair index over 128 x 64 pairs
            int tl = idx >> 6, j = idx & 63;
            int c0 = j*2;
            int w2 = tl >> 5, tt = tl & 31;
            if (tt < sfr[w2]){
                unsigned pr = *(unsigned*)&buf[tl*BPAD + c0];
                float v0 = bf2f(pr & 0xffffu), v1 = bf2f(pr >> 16);
                int p0 = c0 & 63;
                float lr0 = lpre[tt*64 + p0], lr1 = lpre[tt*64 + p0 + 1];
                float li0 = lpim[tt*64 + p0], li1 = lpim[tt*64 + p0 + 1];
                float xr0 = xin_s[w2*128 + p0],      xr1 = xin_s[w2*128 + p0 + 1];
                float xi0 = xin_s[w2*128 + 64 + p0], xi1 = xin_s[w2*128 + 64 + p0 + 1];
                if (c0 < 64){
                    v0 += lr0*xr0 - li0*xi0;
                    v1 += lr1*xr1 - li1*xi1;
                } else {
                    v0 += lr0*xi0 + li0*xr0;
                    v1 += lr1*xi1 + li1*xr1;
                }
                *(unsigned*)&buf[tl*BPAD + c0] = pk2(v0, v1);
            }
        }
    }
    __syncthreads();

    // ---- Phase E: GEMM2  y[t][h] = X[t][c] * W2[h][c] ----
    f32x4 acc2[2][16];
    #pragma unroll
    for (int a = 0; a < 2; a++)
        #pragma unroll
        for (int b = 0; b < 16; b++) acc2[a][b] = (f32x4){0.f,0.f,0.f,0.f};
    {
        const u16t* W2 = wsu + OFF_W2_U;
        #pragma unroll
        for (int ng = 0; ng < 4; ng++){
            #pragma unroll
            for (int kf = 0; kf < 4; kf++){
                const int k0 = kf*32 + q*8;
                short8 a0 = *(const short8*)&buf[(w*SUBT +  0 + m)*BPAD + k0];
                short8 a1 = *(const short8*)&buf[(w*SUBT + 16 + m)*BPAD + k0];
                #pragma unroll
                for (int nj = 0; nj < 4; nj++){
                    int nt = ng*4 + nj;
                    short8 bfr = __builtin_bit_cast(short8, *(const uint4*)(W2 + (nt*16 + m)*C2 + k0));
                    acc2[0][nt] = __builtin_amdgcn_mfma_f32_16x16x32_bf16(a0, bfr, acc2[0][nt], 0,0,0);
                    acc2[1][nt] = __builtin_amdgcn_mfma_f32_16x16x32_bf16(a1, bfr, acc2[1][nt], 0,0,0);
                }
            }
        }
    }

    // ---- Phase F: epilogue  y = acc2 + u*D ----
    #pragma unroll
    for (int nt = 0; nt < 16; nt++){
        int h = nt*16 + m;
        float dv = D[h];
        #pragma unroll
        for (int mt = 0; mt < 2; mt++){
            int tb = tg + mt*16 + q*4;
            #pragma unroll
            for (int r = 0; r < 4; r++){
                float uv = USE_U16 ? bf2f(u16g[(size_t)(tb + r)*H_DIM + h])
                                   : u[(size_t)(tb + r)*H_DIM + h];
                y[(size_t)(tb + r)*H_DIM + h] = fmaf(uv, dv, acc2[mt][nt][r]);
            }
        }
    }
}

extern "C" void kernel_launch(void* const* d_in, const int* in_sizes, int n_in,
                              void* d_out, int out_size, void* d_ws, size_t ws_size,
                              hipStream_t stream){
    const float* u      = (const float*)d_in[0];
    const float* Lre    = (const float*)d_in[1];
    const float* Lim    = (const float*)d_in[2];
    const float* Bre    = (const float*)d_in[3];
    const float* Bim    = (const float*)d_in[4];
    const float* Cre    = (const float*)d_in[5];
    const float* Cim    = (const float*)d_in[6];
    const float* D      = (const float*)d_in[7];
    const float* x0re   = (const float*)d_in[9];
    const float* x0im   = (const float*)d_in[10];
    const int*   dflag  = (const int*)d_in[11];
    const float* deltas = (const float*)d_in[8];
    float* wsf = (float*)d_ws;
    u16t*  wsu = (u16t*)d_ws;
    u16t*  u16g = (u16t*)((char*)d_ws + OFF_U16_B);
    float* y   = (float*)d_out;

    const size_t need = (size_t)OFF_U16_B + (size_t)L_SEQ * H_DIM * 2;
    const bool use16 = (ws_size >= need);

    k0a<<<1, 64, 0, stream>>>(Lre, Lim, deltas, wsf);
    k0b<<<256, 256, 0, stream>>>(Bre, Bim, Cre, Cim, wsf, wsu);
    if (use16){
        kconv<<<4096, 256, 0, stream>>>(u, u16g);
        k1<true ><<<NC, 256, 0, stream>>>(u, u16g, dflag, wsf, wsu);
        k2<<<1, 64, 0, stream>>>(x0re, x0im, wsf);
        k3<true ><<<NC, 256, 0, stream>>>(u, u16g, dflag, D, wsf, wsu, y);
    } else {
        k1<false><<<NC, 256, 0, stream>>>(u, u16g, dflag, wsf, wsu);
        k2<<<1, 64, 0, stream>>>(x0re, x0im, wsf);
        k3<false><<<NC, 256, 0, stream>>>(u, u16g, dflag, D, wsf, wsu, y);
    }
}